// Round 21
// baseline (373.515 us; speedup 1.0000x reference)
//
#include <hip/hip_runtime.h>

#define NN 50000
#define NE 250000
#define NSCAN_BLKS ((NN + 255)/256)
#define EDGE_BLKS ((4*NE + 255)/256)
#define NBUCK 4
#define BSZ ((NN + NBUCK - 1)/NBUCK)

typedef __attribute__((ext_vector_type(8))) short bf16x8;
typedef __attribute__((ext_vector_type(4))) float f32x4;

__device__ inline ushort f2bf(float f) {          // RNE float->bf16
  uint u = __float_as_uint(f);
  return (ushort)((u + 0x7fffu + ((u >> 16) & 1u)) >> 16);
}
__device__ inline float bf2f(ushort b) { return __uint_as_float(((uint)b) << 16); }

// ---------------- small utils ----------------
__global__ __launch_bounds__(256) void zero_ints(int* __restrict__ p, int n) {
  int i = blockIdx.x*256 + threadIdx.x;
  if (i < n) p[i] = 0;
}
__global__ __launch_bounds__(256) void zero_floats(float* __restrict__ p, int n) {
  int i = blockIdx.x*256 + threadIdx.x;
  if (i < n) p[i] = 0.f;
}

// ---------------- unified CSR build (dst-keyed, etype-ordered sub-rows) ----------------
__global__ __launch_bounds__(256) void count_kernel(const int* __restrict__ edges, int* __restrict__ counts) {
  int idx = blockIdx.x*256 + threadIdx.x;
  if (idx >= 4*NE) return;
  int t = idx / NE, e = idx - t*NE;
  int dst = edges[(size_t)t*2*NE + NE + e];
  atomicAdd(&counts[t*NN + dst], 1);
}

__global__ __launch_bounds__(256) void sumdeg_kernel(const int* __restrict__ counts, int* __restrict__ totdeg) {
  int v = blockIdx.x*256 + threadIdx.x;
  if (v < NN) totdeg[v] = counts[v] + counts[NN+v] + counts[2*NN+v] + counts[3*NN+v];
}

__global__ __launch_bounds__(256) void scan1_kernel(const int* __restrict__ in, int* __restrict__ out, int* __restrict__ bsum, int n) {
  __shared__ int sd[256];
  int i = blockIdx.x*256 + threadIdx.x;
  int v = (i < n) ? in[i] : 0;
  sd[threadIdx.x] = v;
  __syncthreads();
  for (int off = 1; off < 256; off <<= 1) {
    int add = (threadIdx.x >= off) ? sd[threadIdx.x - off] : 0;
    __syncthreads();
    sd[threadIdx.x] += add;
    __syncthreads();
  }
  if (i < n) out[i] = sd[threadIdx.x] - v;          // exclusive within block
  if (threadIdx.x == 255) bsum[blockIdx.x] = sd[255];
}

__global__ __launch_bounds__(1024) void scan2_kernel(int* __restrict__ bsum, int nb) {
  __shared__ int sd[1024];
  int i = threadIdx.x;
  int v = (i < nb) ? bsum[i] : 0;
  sd[i] = v;
  __syncthreads();
  for (int off = 1; off < 1024; off <<= 1) {
    int add = (i >= off) ? sd[i - off] : 0;
    __syncthreads();
    sd[i] += add;
    __syncthreads();
  }
  if (i < nb) bsum[i] = sd[i] - v;
}

__global__ __launch_bounds__(256) void scan3b_kernel(int* __restrict__ rp, const int* __restrict__ bsum, int n, int total) {
  int i = blockIdx.x*256 + threadIdx.x;
  if (i < n) rp[i] += bsum[blockIdx.x];
  if (i == 0) rp[n] = total;
}

// cursor for scatter + packed bounds (b0,s1,s2,s3) for gather (one int4 load)
__global__ __launch_bounds__(256) void make_cursor_kernel(const int* __restrict__ rp2, const int* __restrict__ counts,
                                                          int* __restrict__ cursor, int4* __restrict__ bnd4) {
  int v = blockIdx.x*256 + threadIdx.x;
  if (v >= NN) return;
  int b = rp2[v];
  int s1 = b  + counts[v];
  int s2 = s1 + counts[NN+v];
  int s3 = s2 + counts[2*NN+v];
  cursor[v] = b; cursor[NN+v] = s1; cursor[2*NN+v] = s2; cursor[3*NN+v] = s3;
  bnd4[v] = make_int4(b, s1, s2, s3);
  if (v == 0) bnd4[NN] = make_int4(4*NE, 4*NE, 4*NE, 4*NE);
}

// dense dst fill: thread per (t,v) sub-row writes dstmap[q]=t*NN+v for its positions
// (sequential, coalesced-ish writes -> NO dirty-line amplification)
__global__ __launch_bounds__(256) void fill_dst_kernel(const int4* __restrict__ bnd4, int* __restrict__ dstmap) {
  int i = blockIdx.x*256 + threadIdx.x;     // over 4*NN
  if (i >= 4*NN) return;
  int t = i / NN, v = i - t*NN;
  const int4 bb = bnd4[v];
  int lo, hi;
  if (t == 0)      { lo = bb.x; hi = bb.y; }
  else if (t == 1) { lo = bb.y; hi = bb.z; }
  else if (t == 2) { lo = bb.z; hi = bb.w; }
  else             { lo = bb.w; hi = ((const int*)bnd4)[(v+1)*4]; }
  for (int q = lo; q < hi; ++q) dstmap[q] = i;
}

// dst-bucketed scatter: single 4B record col2st[pos] = t*NN+src
__global__ __launch_bounds__(256) void scatter_bucketed(const int* __restrict__ edges, int* __restrict__ cursor,
                                                        int* __restrict__ col2st) {
  const int b = blockIdx.x / EDGE_BLKS;
  const int idx = (blockIdx.x - b*EDGE_BLKS)*256 + threadIdx.x;
  if (idx >= 4*NE) return;
  const int t = idx / NE, e = idx - t*NE;
  const int dst = edges[(size_t)t*2*NE + NE + e];
  if (dst < b*BSZ || dst >= (b+1)*BSZ) return;
  const int src = edges[(size_t)t*2*NE + e];
  const int pos = atomicAdd(&cursor[t*NN + dst], 1);
  col2st[pos] = t*NN + src;
}

// ---------------- input converts (consolidated) ----------------
__global__ __launch_bounds__(256) void convert_x_kernel(const float* __restrict__ x, ushort* __restrict__ xpad) {
  int i = blockIdx.x*256 + threadIdx.x;     // over NN*64
  if (i >= NN*64) return;
  int k = i & 63, n = i >> 6;
  xpad[i] = (k < 23) ? f2bf(x[n*23 + k]) : (ushort)0;
}

// WB3[l][t][c][k] = bf16(W_l[t][k][c]), k padded to 64 — all 3 layers in one dispatch
__global__ __launch_bounds__(256) void convert_wb3_kernel(const float* __restrict__ W0, const float* __restrict__ W1,
                                                          const float* __restrict__ W2, ushort* __restrict__ WB3) {
  int i = blockIdx.x*256 + threadIdx.x;     // over 3*4*128*64
  if (i >= 3*4*128*64) return;
  int l = i / (4*128*64); int r = i - l*(4*128*64);
  int k = r & 63, c = (r >> 6) & 127, t = r >> 13;
  const float* W = (l == 0) ? W0 : (l == 1) ? W1 : W2;
  const int Kin = (l == 0) ? 23 : 64;
  float w = (k < Kin) ? W[((size_t)t*Kin + k)*128 + c] : 0.f;
  WB3[i] = f2bf(w);
}

// wwb3[l][c][k], c=0..15: lr=c>>3, t=(c>>1)&3, h=c&1 — all 3 layers in one dispatch
__global__ __launch_bounds__(256) void walwar3_kernel(const float* __restrict__ W0, const float* __restrict__ W1,
                                                      const float* __restrict__ W2, const float* __restrict__ al0,
                                                      const float* __restrict__ al1, const float* __restrict__ al2,
                                                      const float* __restrict__ ar0, const float* __restrict__ ar1,
                                                      const float* __restrict__ ar2, ushort* __restrict__ wwb3) {
  int i = blockIdx.x*256 + threadIdx.x;     // over 3*16*64
  if (i >= 3*16*64) return;
  int l = i / (16*64); int r = i - l*(16*64);
  int c = r >> 6, k = r & 63;
  int lr = c >> 3, t = (c >> 1) & 3, h = c & 1;
  const float* W  = (l == 0) ? W0 : (l == 1) ? W1 : W2;
  const float* al = (l == 0) ? al0 : (l == 1) ? al1 : al2;
  const float* ar = (l == 0) ? ar0 : (l == 1) ? ar1 : ar2;
  const int Kin = (l == 0) ? 23 : 64;
  float v = 0.f;
  if (k < Kin) {
    const float* A = (lr ? ar : al) + t*128 + h*64;
    const float* wr = W + ((size_t)t*Kin + k)*128 + h*64;
    for (int d = 0; d < 64; ++d) v += wr[d]*A[d];
  }
  wwb3[i] = f2bf(v);
}

// ---------------- elk (layer 0 only): el/er = x @ wwb^T ----------------
__global__ __launch_bounds__(256)
void elk_kernel(const ushort* __restrict__ hbf, const ushort* __restrict__ wwb,
                float* __restrict__ elp, float* __restrict__ erp)
{
  __shared__ ushort BS[16*64];    // 2 KB
  __shared__ float sC[16*66];     // padded stride 66 -> 2-way (free)
  const int tid = threadIdx.x;
  if (tid < 128) ((bf16x8*)BS)[tid] = ((const bf16x8*)wwb)[tid];
  __syncthreads();

  const int wv = tid >> 6, lane = tid & 63;
  const int mrow = lane & 15, kq = lane >> 4;
  const int anode = blockIdx.x*64 + wv*16 + mrow;

  const bf16x8 a0 = *(const bf16x8*)(hbf + (size_t)anode*64 + kq*8);
  const bf16x8 a1 = *(const bf16x8*)(hbf + (size_t)anode*64 + 32 + kq*8);
  const bf16x8 b0 = *(const bf16x8*)(BS + mrow*64 + kq*8);
  const bf16x8 b1 = *(const bf16x8*)(BS + mrow*64 + 32 + kq*8);

  f32x4 acc = (f32x4){0.f,0.f,0.f,0.f};
  acc = __builtin_amdgcn_mfma_f32_16x16x32_bf16(a0, b0, acc, 0, 0, 0);
  acc = __builtin_amdgcn_mfma_f32_16x16x32_bf16(a1, b1, acc, 0, 0, 0);

  #pragma unroll
  for (int r = 0; r < 4; ++r) sC[mrow*66 + wv*16 + kq*4 + r] = acc[r];
  __syncthreads();

  const int t = tid >> 6, n = tid & 63;
  const int node = blockIdx.x*64 + n;
  if (node < NN) {
    float2 e2 = make_float2(sC[(t*2+0)*66 + n], sC[(t*2+1)*66 + n]);
    float2 r2 = make_float2(sC[(8+t*2+0)*66 + n], sC[(8+t*2+1)*66 + n]);
    ((float2*)elp)[(size_t)t*NN + node] = e2;
    ((float2*)erp)[(size_t)t*NN + node] = r2;
  }
}

// ---------------- pexp: per-edge softmax numerators (coalesced col2st/dstmap/out) ----------------
__global__ __launch_bounds__(256)
void pexp_kernel(const int* __restrict__ col2st, const int* __restrict__ dstmap,
                 const float* __restrict__ elp, const float* __restrict__ erp,
                 float2* __restrict__ pexp2)
{
  int q = blockIdx.x*256 + threadIdx.x;
  if (q >= 4*NE) return;
  const int s = col2st[q];                           // coalesced
  const int d = dstmap[q];                           // coalesced
  const float2 e2 = ((const float2*)elp)[s];         // random 8B, L2-hot (1.6 MB)
  const float2 r2 = ((const float2*)erp)[d];
  float u0 = e2.x + r2.x, u1 = e2.y + r2.y;
  u0 = (u0 > 0.f) ? u0 : 0.2f*u0;                    // leaky_relu 0.2
  u1 = (u1 > 0.f) ? u1 : 0.2f*u1;
  pexp2[q] = make_float2(__expf(fminf(u0, 80.f)), __expf(fminf(u1, 80.f)));
}

// ---------------- gather: wave per node, split-wave, 4-edge batches; pure FMA stream ----------------
__global__ __launch_bounds__(256)
void gather_kernel(const ushort* __restrict__ hbf, const float2* __restrict__ pexp2,
                   const int* __restrict__ col2st, const int4* __restrict__ bnd4,
                   ushort* __restrict__ agg)
{
  const int v = __builtin_amdgcn_readfirstlane(blockIdx.x*4 + (threadIdx.x >> 6));
  const int lane = threadIdx.x & 63;
  const int h2 = lane >> 5;            // edge parity of this half-wave
  const int j  = lane & 31;            // dim pair: dims 2j, 2j+1
  const uint* hb32 = (const uint*)hbf;
  uint* agg32 = (uint*)agg;

  const int4 bb = bnd4[v];
  const int b4 = ((const int*)bnd4)[(v+1)*4];
  const int bounds[5] = {bb.x, bb.y, bb.z, bb.w, b4};

  #pragma unroll
  for (int t = 0; t < 4; ++t) {
    const int lo = bounds[t], hi = bounds[t+1];
    const int tbase = t*NN;
    float ox = 0.f, oy = 0.f;
    if (lo < hi) {
      const int cnt2 = (hi - lo - h2 + 1) >> 1;      // this half's edge count
      float sum0 = 0.f, sum1 = 0.f, tx0 = 0.f, ty0 = 0.f, tx1 = 0.f, ty1 = 0.f;
      for (int k0 = 0; k0 < cnt2; k0 += 4) {
        int qq[4], s[4];
        #pragma unroll
        for (int u = 0; u < 4; ++u) {
          const int k = k0 + u;
          qq[u] = (k < cnt2) ? (lo + h2 + 2*k) : lo;      // clamp: always valid
        }
        #pragma unroll
        for (int u = 0; u < 4; ++u) s[u] = col2st[qq[u]];
        float2 pp[4];
        #pragma unroll
        for (int u = 0; u < 4; ++u) pp[u] = pexp2[qq[u]];
        uint w[4];
        #pragma unroll
        for (int u = 0; u < 4; ++u) w[u] = hb32[(uint)(s[u] - tbase)*32u + (uint)j];
        #pragma unroll
        for (int u = 0; u < 4; ++u) {
          float p0 = pp[u].x, p1 = pp[u].y;
          if (k0 + u >= cnt2) { p0 = 0.f; p1 = 0.f; }     // pad
          sum0 += p0; sum1 += p1;
          const float xv0 = __uint_as_float(w[u] << 16);
          const float xv1 = __uint_as_float(w[u] & 0xffff0000u);
          tx0 += p0*xv0; ty0 += p0*xv1;                   // head0
          tx1 += p1*xv0; ty1 += p1*xv1;                   // head1
        }
      }
      sum0 += __shfl_xor(sum0, 32); sum1 += __shfl_xor(sum1, 32);
      tx0 += __shfl_xor(tx0, 32);   ty0 += __shfl_xor(ty0, 32);
      tx1 += __shfl_xor(tx1, 32);   ty1 += __shfl_xor(ty1, 32);
      const float i0 = __builtin_amdgcn_rcpf(sum0);
      const float i1 = __builtin_amdgcn_rcpf(sum1);
      ox = h2 ? tx1*i1 : tx0*i0;                          // my half writes its head
      oy = h2 ? ty1*i1 : ty0*i0;
    }
    const uint pk = (uint)f2bf(ox) | ((uint)f2bf(oy) << 16);
    __builtin_nontemporal_store(pk, &agg32[(size_t)(tbase + v)*64 + h2*32 + j]);
  }
}

// ---------------- transform: M=128, fused next-layer el/er + optional final reduce ----------------
__global__ __launch_bounds__(256)
void transform_kernel(const ushort* __restrict__ agg, const ushort* __restrict__ WB,
                      const float* __restrict__ ball, ushort* __restrict__ hout, int post,
                      const ushort* __restrict__ wwbN, float* __restrict__ elp,
                      float* __restrict__ erp, float* __restrict__ accum, int doReduce)
{
  __shared__ ushort WT[2*128*64];   // 32 KB, swizzled
  __shared__ ushort oS[128][72];    // 18 KB: block's output rows (bf16), padded
  __shared__ float sb[128];
  __shared__ float sred[256];
  const int tid = threadIdx.x;
  if (tid < 128) sb[tid] = 0.25f*(ball[tid] + ball[128+tid] + ball[256+tid] + ball[384+tid]);

  const int wv = tid >> 6, lane = tid & 63;
  const int mrow = lane & 15, kq = lane >> 4;
  const int node0 = blockIdx.x*128;
  const int anode0 = node0 + wv*32 + mrow;     // m-block 0; m-block 1 = +16

  f32x4 acc[2][8];
  #pragma unroll
  for (int m = 0; m < 2; ++m)
    #pragma unroll
    for (int nb = 0; nb < 8; ++nb) acc[m][nb] = (f32x4){0.f,0.f,0.f,0.f};

  for (int tb = 0; tb < 4; tb += 2) {
    __syncthreads();                              // protect WT (and sb on first pass)
    for (int i = tid; i < 2048; i += 256) {       // 16B chunks: rows 0..255 = etypes tb,tb+1
      int row = i >> 3, jj = i & 7;
      bf16x8 val = ((const bf16x8*)WB)[tb*1024 + i];
      *(bf16x8*)((char*)WT + row*128 + ((jj ^ (row & 7))*16)) = val;
    }
    __syncthreads();
    #pragma unroll
    for (int t2 = 0; t2 < 2; ++t2) {
      const int t = tb + t2;
      bf16x8 a[2][4];
      #pragma unroll
      for (int m = 0; m < 2; ++m) {
        const ushort* ar_ = agg + ((size_t)t*NN + anode0 + m*16)*128;
        a[m][0] = __builtin_nontemporal_load((const bf16x8*)(ar_ + kq*8));        // h0 k0-31
        a[m][1] = __builtin_nontemporal_load((const bf16x8*)(ar_ + 32 + kq*8));   // h0 k32-63
        a[m][2] = __builtin_nontemporal_load((const bf16x8*)(ar_ + 64 + kq*8));   // h1 k0-31
        a[m][3] = __builtin_nontemporal_load((const bf16x8*)(ar_ + 96 + kq*8));   // h1 k32-63
      }
      #pragma unroll
      for (int nb = 0; nb < 8; ++nb) {
        const int row = t2*128 + nb*16 + mrow;
        const bf16x8 b0 = *(const bf16x8*)((const char*)WT + row*128 + ((kq       ^ (row&7))*16));
        const bf16x8 b1 = *(const bf16x8*)((const char*)WT + row*128 + (((4 + kq) ^ (row&7))*16));
        const int hs = (nb >> 2)*2;               // 0: head0 (a[.][0,1]), 2: head1 (a[.][2,3])
        #pragma unroll
        for (int m = 0; m < 2; ++m) {
          acc[m][nb] = __builtin_amdgcn_mfma_f32_16x16x32_bf16(a[m][hs],   b0, acc[m][nb], 0, 0, 0);
          acc[m][nb] = __builtin_amdgcn_mfma_f32_16x16x32_bf16(a[m][hs+1], b1, acc[m][nb], 0, 0, 0);
        }
      }
    }
  }

  // ---- epilogue: o -> oS (bf16) ----
  #pragma unroll
  for (int m = 0; m < 2; ++m) {
    const int nl0 = wv*32 + m*16 + kq*4;
    #pragma unroll
    for (int nb = 0; nb < 4; ++nb) {
      const int d = nb*16 + mrow;
      const float bm0 = sb[d], bm1 = sb[64 + d];
      #pragma unroll
      for (int r = 0; r < 4; ++r) {
        float h0 = 0.25f*acc[m][nb][r]   + bm0;
        float h1 = 0.25f*acc[m][nb+4][r] + bm1;
        float o;
        if (post) {
          h0 = fmaxf(h0, 0.f); h1 = fmaxf(h1, 0.f);
          o = 0.5f*(h0 + h1) / fmaxf(sqrtf(h0*h0 + h1*h1), 1e-12f);
        } else {
          o = 0.5f*(h0 + h1);
        }
        oS[nl0 + r][d] = f2bf(o);
      }
    }
  }
  __syncthreads();

  if (hout) {                                     // coalesced hout rows
    for (int i = tid; i < 128*16; i += 256) {
      const int nl = i >> 4, seg = i & 15;
      const int v = node0 + nl;
      if (v < NN) *(ushort4*)&hout[(size_t)v*64 + seg*4] = *(ushort4*)&oS[nl][seg*4];
    }
  }

  if (wwbN) {                                     // next layer's el/er: o @ wwbN^T
    #pragma unroll
    for (int m2 = 0; m2 < 2; ++m2) {
      const int ng = wv*2 + m2;                   // 16-node group 0..7
      const int arow = ng*16 + mrow;
      const bf16x8 a0 = *(const bf16x8*)&oS[arow][kq*8];
      const bf16x8 a1 = *(const bf16x8*)&oS[arow][32 + kq*8];
      const bf16x8 b0 = *(const bf16x8*)(wwbN + mrow*64 + kq*8);
      const bf16x8 b1 = *(const bf16x8*)(wwbN + mrow*64 + 32 + kq*8);
      f32x4 c = (f32x4){0.f,0.f,0.f,0.f};
      c = __builtin_amdgcn_mfma_f32_16x16x32_bf16(a0, b0, c, 0, 0, 0);
      c = __builtin_amdgcn_mfma_f32_16x16x32_bf16(a1, b1, c, 0, 0, 0);
      const int lr = mrow >> 3, t = (mrow >> 1) & 3, h = mrow & 1;
      float* dst = lr ? erp : elp;
      #pragma unroll
      for (int r = 0; r < 4; ++r) {
        const int v = node0 + ng*16 + kq*4 + r;
        if (v < NN) dst[((size_t)t*NN + v)*2 + h] = c[r];
      }
    }
  }

  if (doReduce) {                                 // final node-mean partials
    const int d = tid & 63, g = tid >> 6;
    float s = 0.f;
    for (int nl = g; nl < 128; nl += 4)
      if (node0 + nl < NN) s += bf2f(oS[nl][d]);
    sred[tid] = s;
    __syncthreads();
    if (tid < 64)
      atomicAdd(&accum[tid], sred[tid] + sred[tid+64] + sred[tid+128] + sred[tid+192]);
  }
}

// ---------------- final ----------------
__global__ __launch_bounds__(64) void final_out_kernel(const float* __restrict__ accum, float* __restrict__ out) {
  int d = threadIdx.x;
  if (d < 64) out[d] = accum[d] * (1.0f/NN);
}

// ---------------- launch ----------------
extern "C" void kernel_launch(void* const* d_in, const int* in_sizes, int n_in,
                              void* d_out, int out_size, void* d_ws, size_t ws_size,
                              hipStream_t stream) {
  const float* x     = (const float*)d_in[0];
  const int*   edges = (const int*)d_in[1];
  const float* W[3]  = {(const float*)d_in[2], (const float*)d_in[6], (const float*)d_in[10]};
  const float* al[3] = {(const float*)d_in[3], (const float*)d_in[7], (const float*)d_in[11]};
  const float* ar[3] = {(const float*)d_in[4], (const float*)d_in[8], (const float*)d_in[12]};
  const float* b[3]  = {(const float*)d_in[5], (const float*)d_in[9], (const float*)d_in[13]};

  char* ws = (char*)d_ws;
  auto up = [](size_t x_) { return (x_ + 255) & ~(size_t)255; };

  const size_t szAgg  = ((size_t)4*NN + 128)*128*sizeof(ushort); // 51.2 MB (+pad rows)
  const size_t szElp  = (size_t)4*NN*2*sizeof(float);            // 1.6 MB each
  const size_t szHB   = (size_t)(NN+64)*64*sizeof(ushort);       // 6.4 MB each
  const size_t szWB3  = (size_t)3*4*128*64*sizeof(ushort);       // 192 KB
  const size_t szWWB3 = (size_t)3*16*64*sizeof(ushort);          // 6 KB
  const size_t szCol  = (size_t)4*NE*sizeof(int);                // 4 MB each
  const size_t szPex  = (size_t)4*NE*sizeof(float2);             // 8 MB
  const size_t szBnd  = (size_t)(NN+1)*sizeof(int4);
  const size_t szI4   = (size_t)4*NN*sizeof(int);
  const size_t szI1   = (size_t)(NN+1)*sizeof(int);

  size_t o = 0;
  ushort* agg    = (ushort*)(ws + o); o += up(szAgg);
  float*  elp    = (float*)(ws + o);  o += up(szElp);
  float*  erp    = (float*)(ws + o);  o += up(szElp);
  ushort* xpad   = (ushort*)(ws + o); o += up(szHB);
  ushort* hbuf   = (ushort*)(ws + o); o += up(szHB);
  ushort* WB3    = (ushort*)(ws + o); o += up(szWB3);
  ushort* wwb3   = (ushort*)(ws + o); o += up(szWWB3);
  float*  accum  = (float*)(ws + o);  o += up(256);
  int*    col2st = (int*)(ws + o);    o += up(szCol);
  int*    dstmap = (int*)(ws + o);    o += up(szCol);
  float2* pexp2  = (float2*)(ws + o); o += up(szPex);
  int4*   bnd4   = (int4*)(ws + o);   o += up(szBnd);
  int* row_ptr2  = (int*)(ws + o);    o += up(szI1);
  int* totdeg    = (int*)(ws + o);    o += up(szI1);
  int* cursor    = (int*)(ws + o);    o += up(szI4);
  int* counts    = (int*)(ws + o);    o += up(szI4);
  int* bsum      = (int*)(ws + o);    o += up(4096);

  // ---- weight/x prep (consolidated, once) ----
  convert_wb3_kernel<<<(3*4*128*64 + 255)/256, 256, 0, stream>>>(W[0], W[1], W[2], WB3);
  walwar3_kernel<<<(3*16*64 + 255)/256, 256, 0, stream>>>(W[0], W[1], W[2], al[0], al[1], al[2],
                                                          ar[0], ar[1], ar[2], wwb3);
  convert_x_kernel<<<(NN*64 + 255)/256, 256, 0, stream>>>(x, xpad);

  // ---- unified CSR build (once; shared by all layers) ----
  zero_ints<<<(4*NN + 255)/256, 256, 0, stream>>>(counts, 4*NN);
  count_kernel<<<EDGE_BLKS, 256, 0, stream>>>(edges, counts);
  sumdeg_kernel<<<NSCAN_BLKS, 256, 0, stream>>>(counts, totdeg);
  scan1_kernel<<<NSCAN_BLKS, 256, 0, stream>>>(totdeg, row_ptr2, bsum, NN);
  scan2_kernel<<<1, 1024, 0, stream>>>(bsum, NSCAN_BLKS);
  scan3b_kernel<<<NSCAN_BLKS, 256, 0, stream>>>(row_ptr2, bsum, NN, 4*NE);
  make_cursor_kernel<<<NSCAN_BLKS, 256, 0, stream>>>(row_ptr2, counts, cursor, bnd4);
  fill_dst_kernel<<<(4*NN + 255)/256, 256, 0, stream>>>(bnd4, dstmap);
  scatter_bucketed<<<NBUCK*EDGE_BLKS, 256, 0, stream>>>(edges, cursor, col2st);
  zero_floats<<<1, 64, 0, stream>>>(accum, 64);

  const int gemmGX = (NN + 63)/64;     // 782
  const int tfGX   = (NN + 127)/128;   // 391

  // layer 0 el/er from x
  elk_kernel<<<gemmGX, 256, 0, stream>>>(xpad, wwb3, elp, erp);

  for (int l = 0; l < 3; ++l) {
    const ushort* hin = (l == 0) ? xpad : hbuf;
    const ushort* WB  = WB3 + (size_t)l*4*128*64;
    const ushort* wwbNext = (l < 2) ? (wwb3 + (size_t)(l+1)*16*64) : nullptr;
    pexp_kernel<<<EDGE_BLKS, 256, 0, stream>>>(col2st, dstmap, elp, erp, pexp2);
    gather_kernel<<<NN/4, 256, 0, stream>>>(hin, pexp2, col2st, bnd4, agg);
    transform_kernel<<<tfGX, 256, 0, stream>>>(agg, WB, b[l],
                                               (l < 2) ? hbuf : nullptr, (l < 2) ? 1 : 0,
                                               wwbNext, elp, erp,
                                               accum, (l == 2) ? 1 : 0);
  }

  final_out_kernel<<<1, 64, 0, stream>>>(accum, (float*)d_out);
}

// Round 22
// 365.328 us; speedup vs baseline: 1.0224x; 1.0224x over previous
//
#include <hip/hip_runtime.h>

#define NN 50000
#define NE 250000
#define NSCAN_BLKS ((NN + 255)/256)
#define EDGE_BLKS ((4*NE + 255)/256)
#define NBUCK 8
#define BSZ ((NN + NBUCK - 1)/NBUCK)

typedef __attribute__((ext_vector_type(8))) short bf16x8;
typedef __attribute__((ext_vector_type(4))) float f32x4;

__device__ inline ushort f2bf(float f) {          // RNE float->bf16
  uint u = __float_as_uint(f);
  return (ushort)((u + 0x7fffu + ((u >> 16) & 1u)) >> 16);
}
__device__ inline float bf2f(ushort b) { return __uint_as_float(((uint)b) << 16); }

// ---------------- small utils ----------------
__global__ __launch_bounds__(256) void zero_ints(int* __restrict__ p, int n) {
  int i = blockIdx.x*256 + threadIdx.x;
  if (i < n) p[i] = 0;
}
__global__ __launch_bounds__(256) void zero_floats(float* __restrict__ p, int n) {
  int i = blockIdx.x*256 + threadIdx.x;
  if (i < n) p[i] = 0.f;
}

// ---------------- unified CSR build (dst-keyed, etype-ordered sub-rows) ----------------
__global__ __launch_bounds__(256) void count_kernel(const int* __restrict__ edges, int* __restrict__ counts) {
  int idx = blockIdx.x*256 + threadIdx.x;
  if (idx >= 4*NE) return;
  int t = idx / NE, e = idx - t*NE;
  int dst = edges[(size_t)t*2*NE + NE + e];
  atomicAdd(&counts[t*NN + dst], 1);
}

__global__ __launch_bounds__(256) void sumdeg_kernel(const int* __restrict__ counts, int* __restrict__ totdeg) {
  int v = blockIdx.x*256 + threadIdx.x;
  if (v < NN) totdeg[v] = counts[v] + counts[NN+v] + counts[2*NN+v] + counts[3*NN+v];
}

__global__ __launch_bounds__(256) void scan1_kernel(const int* __restrict__ in, int* __restrict__ out, int* __restrict__ bsum, int n) {
  __shared__ int sd[256];
  int i = blockIdx.x*256 + threadIdx.x;
  int v = (i < n) ? in[i] : 0;
  sd[threadIdx.x] = v;
  __syncthreads();
  for (int off = 1; off < 256; off <<= 1) {
    int add = (threadIdx.x >= off) ? sd[threadIdx.x - off] : 0;
    __syncthreads();
    sd[threadIdx.x] += add;
    __syncthreads();
  }
  if (i < n) out[i] = sd[threadIdx.x] - v;          // exclusive within block
  if (threadIdx.x == 255) bsum[blockIdx.x] = sd[255];
}

__global__ __launch_bounds__(1024) void scan2_kernel(int* __restrict__ bsum, int nb) {
  __shared__ int sd[1024];
  int i = threadIdx.x;
  int v = (i < nb) ? bsum[i] : 0;
  sd[i] = v;
  __syncthreads();
  for (int off = 1; off < 1024; off <<= 1) {
    int add = (i >= off) ? sd[i - off] : 0;
    __syncthreads();
    sd[i] += add;
    __syncthreads();
  }
  if (i < nb) bsum[i] = sd[i] - v;
}

__global__ __launch_bounds__(256) void scan3b_kernel(int* __restrict__ rp, const int* __restrict__ bsum, int n, int total) {
  int i = blockIdx.x*256 + threadIdx.x;
  if (i < n) rp[i] += bsum[blockIdx.x];
  if (i == 0) rp[n] = total;
}

// cursor for scatter + packed bounds (b0,s1,s2,s3) for gather (one int4 load)
__global__ __launch_bounds__(256) void make_cursor_kernel(const int* __restrict__ rp2, const int* __restrict__ counts,
                                                          int* __restrict__ cursor, int4* __restrict__ bnd4) {
  int v = blockIdx.x*256 + threadIdx.x;
  if (v >= NN) return;
  int b = rp2[v];
  int s1 = b  + counts[v];
  int s2 = s1 + counts[NN+v];
  int s3 = s2 + counts[2*NN+v];
  cursor[v] = b; cursor[NN+v] = s1; cursor[2*NN+v] = s2; cursor[3*NN+v] = s3;
  bnd4[v] = make_int4(b, s1, s2, s3);
  if (v == 0) bnd4[NN] = make_int4(4*NE, 4*NE, 4*NE, 4*NE);
}

// dense dst fill: thread per (t,v) sub-row writes dstmap[q]=t*NN+v for its positions
__global__ __launch_bounds__(256) void fill_dst_kernel(const int4* __restrict__ bnd4, int* __restrict__ dstmap) {
  int i = blockIdx.x*256 + threadIdx.x;     // over 4*NN
  if (i >= 4*NN) return;
  int t = i / NN, v = i - t*NN;
  const int4 bb = bnd4[v];
  int lo, hi;
  if (t == 0)      { lo = bb.x; hi = bb.y; }
  else if (t == 1) { lo = bb.y; hi = bb.z; }
  else if (t == 2) { lo = bb.z; hi = bb.w; }
  else             { lo = bb.w; hi = ((const int*)bnd4)[(v+1)*4]; }
  for (int q = lo; q < hi; ++q) dstmap[q] = i;
}

// XCD-affine scatter: bucket = blockIdx.x & 7. With round-robin blockIdx->XCD mapping,
// all writers of bucket b run on XCD b -> each col2st dirty line lives in ONE L2 and is
// written back once (kills the cross-XCD partial-line writeback amplification).
__global__ __launch_bounds__(256) void scatter_xcd(const int* __restrict__ edges, int* __restrict__ cursor,
                                                   int* __restrict__ col2st) {
  const int b = blockIdx.x & (NBUCK-1);
  const int idx = (blockIdx.x >> 3)*256 + threadIdx.x;
  if (idx >= 4*NE) return;
  const int t = idx / NE, e = idx - t*NE;
  const int dst = edges[(size_t)t*2*NE + NE + e];
  if (dst < b*BSZ || dst >= (b+1)*BSZ) return;
  const int src = edges[(size_t)t*2*NE + e];
  const int pos = atomicAdd(&cursor[t*NN + dst], 1);
  col2st[pos] = t*NN + src;
}

// ---------------- input converts (consolidated) ----------------
__global__ __launch_bounds__(256) void convert_x_kernel(const float* __restrict__ x, ushort* __restrict__ xpad) {
  int i = blockIdx.x*256 + threadIdx.x;     // over NN*64
  if (i >= NN*64) return;
  int k = i & 63, n = i >> 6;
  xpad[i] = (k < 23) ? f2bf(x[n*23 + k]) : (ushort)0;
}

// WB3[l][t][c][k] = bf16(W_l[t][k][c]), k padded to 64 — all 3 layers in one dispatch
__global__ __launch_bounds__(256) void convert_wb3_kernel(const float* __restrict__ W0, const float* __restrict__ W1,
                                                          const float* __restrict__ W2, ushort* __restrict__ WB3) {
  int i = blockIdx.x*256 + threadIdx.x;     // over 3*4*128*64
  if (i >= 3*4*128*64) return;
  int l = i / (4*128*64); int r = i - l*(4*128*64);
  int k = r & 63, c = (r >> 6) & 127, t = r >> 13;
  const float* W = (l == 0) ? W0 : (l == 1) ? W1 : W2;
  const int Kin = (l == 0) ? 23 : 64;
  float w = (k < Kin) ? W[((size_t)t*Kin + k)*128 + c] : 0.f;
  WB3[i] = f2bf(w);
}

// wwb3[l][c][k], c=0..15: lr=c>>3, t=(c>>1)&3, h=c&1 — all 3 layers in one dispatch
__global__ __launch_bounds__(256) void walwar3_kernel(const float* __restrict__ W0, const float* __restrict__ W1,
                                                      const float* __restrict__ W2, const float* __restrict__ al0,
                                                      const float* __restrict__ al1, const float* __restrict__ al2,
                                                      const float* __restrict__ ar0, const float* __restrict__ ar1,
                                                      const float* __restrict__ ar2, ushort* __restrict__ wwb3) {
  int i = blockIdx.x*256 + threadIdx.x;     // over 3*16*64
  if (i >= 3*16*64) return;
  int l = i / (16*64); int r = i - l*(16*64);
  int c = r >> 6, k = r & 63;
  int lr = c >> 3, t = (c >> 1) & 3, h = c & 1;
  const float* W  = (l == 0) ? W0 : (l == 1) ? W1 : W2;
  const float* al = (l == 0) ? al0 : (l == 1) ? al1 : al2;
  const float* ar = (l == 0) ? ar0 : (l == 1) ? ar1 : ar2;
  const int Kin = (l == 0) ? 23 : 64;
  float v = 0.f;
  if (k < Kin) {
    const float* A = (lr ? ar : al) + t*128 + h*64;
    const float* wr = W + ((size_t)t*Kin + k)*128 + h*64;
    for (int d = 0; d < 64; ++d) v += wr[d]*A[d];
  }
  wwb3[i] = f2bf(v);
}

// ---------------- elk (layer 0 only): el/er = x @ wwb^T ----------------
__global__ __launch_bounds__(256)
void elk_kernel(const ushort* __restrict__ hbf, const ushort* __restrict__ wwb,
                float* __restrict__ elp, float* __restrict__ erp)
{
  __shared__ ushort BS[16*64];    // 2 KB
  __shared__ float sC[16*66];     // padded stride 66 -> 2-way (free)
  const int tid = threadIdx.x;
  if (tid < 128) ((bf16x8*)BS)[tid] = ((const bf16x8*)wwb)[tid];
  __syncthreads();

  const int wv = tid >> 6, lane = tid & 63;
  const int mrow = lane & 15, kq = lane >> 4;
  const int anode = blockIdx.x*64 + wv*16 + mrow;

  const bf16x8 a0 = *(const bf16x8*)(hbf + (size_t)anode*64 + kq*8);
  const bf16x8 a1 = *(const bf16x8*)(hbf + (size_t)anode*64 + 32 + kq*8);
  const bf16x8 b0 = *(const bf16x8*)(BS + mrow*64 + kq*8);
  const bf16x8 b1 = *(const bf16x8*)(BS + mrow*64 + 32 + kq*8);

  f32x4 acc = (f32x4){0.f,0.f,0.f,0.f};
  acc = __builtin_amdgcn_mfma_f32_16x16x32_bf16(a0, b0, acc, 0, 0, 0);
  acc = __builtin_amdgcn_mfma_f32_16x16x32_bf16(a1, b1, acc, 0, 0, 0);

  #pragma unroll
  for (int r = 0; r < 4; ++r) sC[mrow*66 + wv*16 + kq*4 + r] = acc[r];
  __syncthreads();

  const int t = tid >> 6, n = tid & 63;
  const int node = blockIdx.x*64 + n;
  if (node < NN) {
    float2 e2 = make_float2(sC[(t*2+0)*66 + n], sC[(t*2+1)*66 + n]);
    float2 r2 = make_float2(sC[(8+t*2+0)*66 + n], sC[(8+t*2+1)*66 + n]);
    ((float2*)elp)[(size_t)t*NN + node] = e2;
    ((float2*)erp)[(size_t)t*NN + node] = r2;
  }
}

// ---------------- pexp: per-edge softmax numerators (coalesced col2st/dstmap/out) ----------------
__global__ __launch_bounds__(256)
void pexp_kernel(const int* __restrict__ col2st, const int* __restrict__ dstmap,
                 const float* __restrict__ elp, const float* __restrict__ erp,
                 float2* __restrict__ pexp2)
{
  int q = blockIdx.x*256 + threadIdx.x;
  if (q >= 4*NE) return;
  const int s = col2st[q];                           // coalesced
  const int d = dstmap[q];                           // coalesced
  const float2 e2 = ((const float2*)elp)[s];         // random 8B, L2-hot (1.6 MB)
  const float2 r2 = ((const float2*)erp)[d];
  float u0 = e2.x + r2.x, u1 = e2.y + r2.y;
  u0 = (u0 > 0.f) ? u0 : 0.2f*u0;                    // leaky_relu 0.2
  u1 = (u1 > 0.f) ? u1 : 0.2f*u1;
  pexp2[q] = make_float2(__expf(fminf(u0, 80.f)), __expf(fminf(u1, 80.f)));
}

// ---------------- gather: wave per node, split-wave, 4-edge batches; pure FMA stream ----------------
__global__ __launch_bounds__(256)
void gather_kernel(const ushort* __restrict__ hbf, const float2* __restrict__ pexp2,
                   const int* __restrict__ col2st, const int4* __restrict__ bnd4,
                   ushort* __restrict__ agg)
{
  const int v = __builtin_amdgcn_readfirstlane(blockIdx.x*4 + (threadIdx.x >> 6));
  const int lane = threadIdx.x & 63;
  const int h2 = lane >> 5;            // edge parity of this half-wave
  const int j  = lane & 31;            // dim pair: dims 2j, 2j+1
  const uint* hb32 = (const uint*)hbf;
  uint* agg32 = (uint*)agg;

  const int4 bb = bnd4[v];
  const int b4 = ((const int*)bnd4)[(v+1)*4];
  const int bounds[5] = {bb.x, bb.y, bb.z, bb.w, b4};

  #pragma unroll
  for (int t = 0; t < 4; ++t) {
    const int lo = bounds[t], hi = bounds[t+1];
    const int tbase = t*NN;
    float ox = 0.f, oy = 0.f;
    if (lo < hi) {
      const int cnt2 = (hi - lo - h2 + 1) >> 1;      // this half's edge count
      float sum0 = 0.f, sum1 = 0.f, tx0 = 0.f, ty0 = 0.f, tx1 = 0.f, ty1 = 0.f;
      for (int k0 = 0; k0 < cnt2; k0 += 4) {
        int qq[4], s[4];
        #pragma unroll
        for (int u = 0; u < 4; ++u) {
          const int k = k0 + u;
          qq[u] = (k < cnt2) ? (lo + h2 + 2*k) : lo;      // clamp: always valid
        }
        #pragma unroll
        for (int u = 0; u < 4; ++u) s[u] = col2st[qq[u]];
        float2 pp[4];
        #pragma unroll
        for (int u = 0; u < 4; ++u) pp[u] = pexp2[qq[u]];
        uint w[4];
        #pragma unroll
        for (int u = 0; u < 4; ++u) w[u] = hb32[(uint)(s[u] - tbase)*32u + (uint)j];
        #pragma unroll
        for (int u = 0; u < 4; ++u) {
          float p0 = pp[u].x, p1 = pp[u].y;
          if (k0 + u >= cnt2) { p0 = 0.f; p1 = 0.f; }     // pad
          sum0 += p0; sum1 += p1;
          const float xv0 = __uint_as_float(w[u] << 16);
          const float xv1 = __uint_as_float(w[u] & 0xffff0000u);
          tx0 += p0*xv0; ty0 += p0*xv1;                   // head0
          tx1 += p1*xv0; ty1 += p1*xv1;                   // head1
        }
      }
      sum0 += __shfl_xor(sum0, 32); sum1 += __shfl_xor(sum1, 32);
      tx0 += __shfl_xor(tx0, 32);   ty0 += __shfl_xor(ty0, 32);
      tx1 += __shfl_xor(tx1, 32);   ty1 += __shfl_xor(ty1, 32);
      const float i0 = __builtin_amdgcn_rcpf(sum0);
      const float i1 = __builtin_amdgcn_rcpf(sum1);
      ox = h2 ? tx1*i1 : tx0*i0;                          // my half writes its head
      oy = h2 ? ty1*i1 : ty0*i0;
    }
    const uint pk = (uint)f2bf(ox) | ((uint)f2bf(oy) << 16);
    __builtin_nontemporal_store(pk, &agg32[(size_t)(tbase + v)*64 + h2*32 + j]);
  }
}

// ---------------- transform: M=128, fused next-layer el/er + optional final reduce ----------------
__global__ __launch_bounds__(256)
void transform_kernel(const ushort* __restrict__ agg, const ushort* __restrict__ WB,
                      const float* __restrict__ ball, ushort* __restrict__ hout, int post,
                      const ushort* __restrict__ wwbN, float* __restrict__ elp,
                      float* __restrict__ erp, float* __restrict__ accum, int doReduce)
{
  __shared__ ushort WT[2*128*64];   // 32 KB, swizzled
  __shared__ ushort oS[128][72];    // 18 KB: block's output rows (bf16), padded
  __shared__ float sb[128];
  __shared__ float sred[256];
  const int tid = threadIdx.x;
  if (tid < 128) sb[tid] = 0.25f*(ball[tid] + ball[128+tid] + ball[256+tid] + ball[384+tid]);

  const int wv = tid >> 6, lane = tid & 63;
  const int mrow = lane & 15, kq = lane >> 4;
  const int node0 = blockIdx.x*128;
  const int anode0 = node0 + wv*32 + mrow;     // m-block 0; m-block 1 = +16

  f32x4 acc[2][8];
  #pragma unroll
  for (int m = 0; m < 2; ++m)
    #pragma unroll
    for (int nb = 0; nb < 8; ++nb) acc[m][nb] = (f32x4){0.f,0.f,0.f,0.f};

  for (int tb = 0; tb < 4; tb += 2) {
    __syncthreads();                              // protect WT (and sb on first pass)
    for (int i = tid; i < 2048; i += 256) {       // 16B chunks: rows 0..255 = etypes tb,tb+1
      int row = i >> 3, jj = i & 7;
      bf16x8 val = ((const bf16x8*)WB)[tb*1024 + i];
      *(bf16x8*)((char*)WT + row*128 + ((jj ^ (row & 7))*16)) = val;
    }
    __syncthreads();
    #pragma unroll
    for (int t2 = 0; t2 < 2; ++t2) {
      const int t = tb + t2;
      bf16x8 a[2][4];
      #pragma unroll
      for (int m = 0; m < 2; ++m) {
        const ushort* ar_ = agg + ((size_t)t*NN + anode0 + m*16)*128;
        a[m][0] = __builtin_nontemporal_load((const bf16x8*)(ar_ + kq*8));        // h0 k0-31
        a[m][1] = __builtin_nontemporal_load((const bf16x8*)(ar_ + 32 + kq*8));   // h0 k32-63
        a[m][2] = __builtin_nontemporal_load((const bf16x8*)(ar_ + 64 + kq*8));   // h1 k0-31
        a[m][3] = __builtin_nontemporal_load((const bf16x8*)(ar_ + 96 + kq*8));   // h1 k32-63
      }
      #pragma unroll
      for (int nb = 0; nb < 8; ++nb) {
        const int row = t2*128 + nb*16 + mrow;
        const bf16x8 b0 = *(const bf16x8*)((const char*)WT + row*128 + ((kq       ^ (row&7))*16));
        const bf16x8 b1 = *(const bf16x8*)((const char*)WT + row*128 + (((4 + kq) ^ (row&7))*16));
        const int hs = (nb >> 2)*2;               // 0: head0 (a[.][0,1]), 2: head1 (a[.][2,3])
        #pragma unroll
        for (int m = 0; m < 2; ++m) {
          acc[m][nb] = __builtin_amdgcn_mfma_f32_16x16x32_bf16(a[m][hs],   b0, acc[m][nb], 0, 0, 0);
          acc[m][nb] = __builtin_amdgcn_mfma_f32_16x16x32_bf16(a[m][hs+1], b1, acc[m][nb], 0, 0, 0);
        }
      }
    }
  }

  // ---- epilogue: o -> oS (bf16) ----
  #pragma unroll
  for (int m = 0; m < 2; ++m) {
    const int nl0 = wv*32 + m*16 + kq*4;
    #pragma unroll
    for (int nb = 0; nb < 4; ++nb) {
      const int d = nb*16 + mrow;
      const float bm0 = sb[d], bm1 = sb[64 + d];
      #pragma unroll
      for (int r = 0; r < 4; ++r) {
        float h0 = 0.25f*acc[m][nb][r]   + bm0;
        float h1 = 0.25f*acc[m][nb+4][r] + bm1;
        float o;
        if (post) {
          h0 = fmaxf(h0, 0.f); h1 = fmaxf(h1, 0.f);
          o = 0.5f*(h0 + h1) / fmaxf(sqrtf(h0*h0 + h1*h1), 1e-12f);
        } else {
          o = 0.5f*(h0 + h1);
        }
        oS[nl0 + r][d] = f2bf(o);
      }
    }
  }
  __syncthreads();

  if (hout) {                                     // coalesced hout rows
    for (int i = tid; i < 128*16; i += 256) {
      const int nl = i >> 4, seg = i & 15;
      const int v = node0 + nl;
      if (v < NN) *(ushort4*)&hout[(size_t)v*64 + seg*4] = *(ushort4*)&oS[nl][seg*4];
    }
  }

  if (wwbN) {                                     // next layer's el/er: o @ wwbN^T
    #pragma unroll
    for (int m2 = 0; m2 < 2; ++m2) {
      const int ng = wv*2 + m2;                   // 16-node group 0..7
      const int arow = ng*16 + mrow;
      const bf16x8 a0 = *(const bf16x8*)&oS[arow][kq*8];
      const bf16x8 a1 = *(const bf16x8*)&oS[arow][32 + kq*8];
      const bf16x8 b0 = *(const bf16x8*)(wwbN + mrow*64 + kq*8);
      const bf16x8 b1 = *(const bf16x8*)(wwbN + mrow*64 + 32 + kq*8);
      f32x4 c = (f32x4){0.f,0.f,0.f,0.f};
      c = __builtin_amdgcn_mfma_f32_16x16x32_bf16(a0, b0, c, 0, 0, 0);
      c = __builtin_amdgcn_mfma_f32_16x16x32_bf16(a1, b1, c, 0, 0, 0);
      const int lr = mrow >> 3, t = (mrow >> 1) & 3, h = mrow & 1;
      float* dst = lr ? erp : elp;
      #pragma unroll
      for (int r = 0; r < 4; ++r) {
        const int v = node0 + ng*16 + kq*4 + r;
        if (v < NN) dst[((size_t)t*NN + v)*2 + h] = c[r];
      }
    }
  }

  if (doReduce) {                                 // final node-mean partials
    const int d = tid & 63, g = tid >> 6;
    float s = 0.f;
    for (int nl = g; nl < 128; nl += 4)
      if (node0 + nl < NN) s += bf2f(oS[nl][d]);
    sred[tid] = s;
    __syncthreads();
    if (tid < 64)
      atomicAdd(&accum[tid], sred[tid] + sred[tid+64] + sred[tid+128] + sred[tid+192]);
  }
}

// ---------------- final ----------------
__global__ __launch_bounds__(64) void final_out_kernel(const float* __restrict__ accum, float* __restrict__ out) {
  int d = threadIdx.x;
  if (d < 64) out[d] = accum[d] * (1.0f/NN);
}

// ---------------- launch ----------------
extern "C" void kernel_launch(void* const* d_in, const int* in_sizes, int n_in,
                              void* d_out, int out_size, void* d_ws, size_t ws_size,
                              hipStream_t stream) {
  const float* x     = (const float*)d_in[0];
  const int*   edges = (const int*)d_in[1];
  const float* W[3]  = {(const float*)d_in[2], (const float*)d_in[6], (const float*)d_in[10]};
  const float* al[3] = {(const float*)d_in[3], (const float*)d_in[7], (const float*)d_in[11]};
  const float* ar[3] = {(const float*)d_in[4], (const float*)d_in[8], (const float*)d_in[12]};
  const float* b[3]  = {(const float*)d_in[5], (const float*)d_in[9], (const float*)d_in[13]};

  char* ws = (char*)d_ws;
  auto up = [](size_t x_) { return (x_ + 255) & ~(size_t)255; };

  const size_t szAgg  = ((size_t)4*NN + 128)*128*sizeof(ushort); // 51.2 MB (+pad rows)
  const size_t szElp  = (size_t)4*NN*2*sizeof(float);            // 1.6 MB each
  const size_t szHB   = (size_t)(NN+64)*64*sizeof(ushort);       // 6.4 MB each
  const size_t szWB3  = (size_t)3*4*128*64*sizeof(ushort);       // 192 KB
  const size_t szWWB3 = (size_t)3*16*64*sizeof(ushort);          // 6 KB
  const size_t szCol  = (size_t)4*NE*sizeof(int);                // 4 MB each
  const size_t szPex  = (size_t)4*NE*sizeof(float2);             // 8 MB
  const size_t szBnd  = (size_t)(NN+1)*sizeof(int4);
  const size_t szI4   = (size_t)4*NN*sizeof(int);
  const size_t szI1   = (size_t)(NN+1)*sizeof(int);

  size_t o = 0;
  ushort* agg    = (ushort*)(ws + o); o += up(szAgg);
  float*  elp    = (float*)(ws + o);  o += up(szElp);
  float*  erp    = (float*)(ws + o);  o += up(szElp);
  ushort* xpad   = (ushort*)(ws + o); o += up(szHB);
  ushort* hbuf   = (ushort*)(ws + o); o += up(szHB);
  ushort* WB3    = (ushort*)(ws + o); o += up(szWB3);
  ushort* wwb3   = (ushort*)(ws + o); o += up(szWWB3);
  float*  accum  = (float*)(ws + o);  o += up(256);
  int*    col2st = (int*)(ws + o);    o += up(szCol);
  int*    dstmap = (int*)(ws + o);    o += up(szCol);
  float2* pexp2  = (float2*)(ws + o); o += up(szPex);
  int4*   bnd4   = (int4*)(ws + o);   o += up(szBnd);
  int* row_ptr2  = (int*)(ws + o);    o += up(szI1);
  int* totdeg    = (int*)(ws + o);    o += up(szI1);
  int* cursor    = (int*)(ws + o);    o += up(szI4);
  int* counts    = (int*)(ws + o);    o += up(szI4);
  int* bsum      = (int*)(ws + o);    o += up(4096);

  // ---- weight/x prep (consolidated, once) ----
  convert_wb3_kernel<<<(3*4*128*64 + 255)/256, 256, 0, stream>>>(W[0], W[1], W[2], WB3);
  walwar3_kernel<<<(3*16*64 + 255)/256, 256, 0, stream>>>(W[0], W[1], W[2], al[0], al[1], al[2],
                                                          ar[0], ar[1], ar[2], wwb3);
  convert_x_kernel<<<(NN*64 + 255)/256, 256, 0, stream>>>(x, xpad);

  // ---- unified CSR build (once; shared by all layers) ----
  zero_ints<<<(4*NN + 255)/256, 256, 0, stream>>>(counts, 4*NN);
  count_kernel<<<EDGE_BLKS, 256, 0, stream>>>(edges, counts);
  sumdeg_kernel<<<NSCAN_BLKS, 256, 0, stream>>>(counts, totdeg);
  scan1_kernel<<<NSCAN_BLKS, 256, 0, stream>>>(totdeg, row_ptr2, bsum, NN);
  scan2_kernel<<<1, 1024, 0, stream>>>(bsum, NSCAN_BLKS);
  scan3b_kernel<<<NSCAN_BLKS, 256, 0, stream>>>(row_ptr2, bsum, NN, 4*NE);
  make_cursor_kernel<<<NSCAN_BLKS, 256, 0, stream>>>(row_ptr2, counts, cursor, bnd4);
  fill_dst_kernel<<<(4*NN + 255)/256, 256, 0, stream>>>(bnd4, dstmap);
  scatter_xcd<<<NBUCK*EDGE_BLKS, 256, 0, stream>>>(edges, cursor, col2st);
  zero_floats<<<1, 64, 0, stream>>>(accum, 64);

  const int gemmGX = (NN + 63)/64;     // 782
  const int tfGX   = (NN + 127)/128;   // 391

  // layer 0 el/er from x
  elk_kernel<<<gemmGX, 256, 0, stream>>>(xpad, wwb3, elp, erp);

  for (int l = 0; l < 3; ++l) {
    const ushort* hin = (l == 0) ? xpad : hbuf;
    const ushort* WB  = WB3 + (size_t)l*4*128*64;
    const ushort* wwbNext = (l < 2) ? (wwb3 + (size_t)(l+1)*16*64) : nullptr;
    pexp_kernel<<<EDGE_BLKS, 256, 0, stream>>>(col2st, dstmap, elp, erp, pexp2);
    gather_kernel<<<NN/4, 256, 0, stream>>>(hin, pexp2, col2st, bnd4, agg);
    transform_kernel<<<tfGX, 256, 0, stream>>>(agg, WB, b[l],
                                               (l < 2) ? hbuf : nullptr, (l < 2) ? 1 : 0,
                                               wwbNext, elp, erp,
                                               accum, (l == 2) ? 1 : 0);
  }

  final_out_kernel<<<1, 64, 0, stream>>>(accum, (float*)d_out);
}